// Round 1
// baseline (1003.511 us; speedup 1.0000x reference)
//
#include <hip/hip_runtime.h>

#define NB 64     // batch
#define NV 197    // visual tokens
#define NL 64     // text tokens
#define ND 768    // input dim
#define NE 256    // embed dim

// ---------------- Kernel 1: cls projection (B x D) @ (D x E) + bias ----------------
__global__ __launch_bounds__(256) void cls_kernel(const float* __restrict__ x,
                                                  const float* __restrict__ W,
                                                  const float* __restrict__ bias,
                                                  float* __restrict__ out) {
  __shared__ float xs[ND];
  const int b = blockIdx.x;
  const int tid = threadIdx.x;
  const float* xr = x + b * ND;
  for (int i = tid; i < ND; i += 256) xs[i] = xr[i];
  __syncthreads();
  float acc = bias[tid];
#pragma unroll 8
  for (int k = 0; k < ND; ++k) acc += xs[k] * W[k * NE + tid];
  out[b * NE + tid] = acc;
}

// ---------------- Kernel 2: token projection + l2norm ----------------
// rows (multiple of 32) x 768 @ 768 x 256, then per-row l2 normalize.
// Block tile: 32 rows x 256 cols. Threads: 256 = 4 row-groups(8 rows) x 64 col-groups(4 cols).
__global__ __launch_bounds__(256) void tok_kernel(const float* __restrict__ X,
                                                  const float* __restrict__ W,
                                                  const float* __restrict__ bias,
                                                  float* __restrict__ out) {
  __shared__ float a_lds[32 * 32];       // 4 KB
  __shared__ float w_lds[32 * 256];      // 32 KB
  const int tid = threadIdx.x;
  const int cx = tid & 63;      // col group: cols cx*4..cx*4+3
  const int ry = tid >> 6;      // row group: rows ry*8..ry*8+7
  const int row0 = blockIdx.x * 32;

  float acc[8][4];
#pragma unroll
  for (int r = 0; r < 8; ++r)
#pragma unroll
    for (int j = 0; j < 4; ++j) acc[r][j] = 0.0f;

  for (int kc = 0; kc < ND; kc += 32) {
    // stage A tile: 32 rows x 32 k  (256 float4, one per thread)
    {
      const int r = tid >> 3;
      const int kq = tid & 7;
      *(float4*)&a_lds[r * 32 + kq * 4] =
          *(const float4*)&X[(row0 + r) * ND + kc + kq * 4];
    }
    // stage W tile: 32 k x 256 cols (2048 float4, 8 per thread)
#pragma unroll
    for (int it = 0; it < 8; ++it) {
      const int id = it * 256 + tid;
      const int k = id >> 6;
      const int c4 = id & 63;
      *(float4*)&w_lds[k * 256 + c4 * 4] =
          *(const float4*)&W[(kc + k) * NE + c4 * 4];
    }
    __syncthreads();

#pragma unroll
    for (int kk = 0; kk < 8; ++kk) {
      float a[8][4], w[4][4];
#pragma unroll
      for (int r = 0; r < 8; ++r) {
        float4 v4 = *(const float4*)&a_lds[(ry * 8 + r) * 32 + kk * 4];
        a[r][0] = v4.x; a[r][1] = v4.y; a[r][2] = v4.z; a[r][3] = v4.w;
      }
#pragma unroll
      for (int u = 0; u < 4; ++u) {
        float4 v4 = *(const float4*)&w_lds[(kk * 4 + u) * 256 + cx * 4];
        w[u][0] = v4.x; w[u][1] = v4.y; w[u][2] = v4.z; w[u][3] = v4.w;
      }
#pragma unroll
      for (int u = 0; u < 4; ++u)
#pragma unroll
        for (int r = 0; r < 8; ++r)
#pragma unroll
          for (int j = 0; j < 4; ++j) acc[r][j] += a[r][u] * w[u][j];
    }
    __syncthreads();
  }

  // epilogue: bias, row l2-norm (all 64 lanes of a wave share the same 8 rows)
  const float4 b4 = *(const float4*)&bias[cx * 4];
#pragma unroll
  for (int r = 0; r < 8; ++r) {
    acc[r][0] += b4.x; acc[r][1] += b4.y; acc[r][2] += b4.z; acc[r][3] += b4.w;
    float ssq = acc[r][0] * acc[r][0] + acc[r][1] * acc[r][1] +
                acc[r][2] * acc[r][2] + acc[r][3] * acc[r][3];
#pragma unroll
    for (int off = 32; off > 0; off >>= 1) ssq += __shfl_xor(ssq, off);
    const float scale = 1.0f / fmaxf(sqrtf(ssq), 1e-12f);
    float4 o;
    o.x = acc[r][0] * scale; o.y = acc[r][1] * scale;
    o.z = acc[r][2] * scale; o.w = acc[r][3] * scale;
    *(float4*)&out[(row0 + ry * 8 + r) * NE + cx * 4] = o;
  }
}

// ---------------- Kernel 3: chamfer similarity ----------------
// One block per (b,q). S = v_tok[b] (197x256) . t_tok[q]^T (64x256).
// i2t[b,q] = sum_v max_t S / 197 ; t2i[b,q] = sum_{t<len[b]} max_v S / len[b].
__global__ __launch_bounds__(256) void sim_kernel(const float* __restrict__ vt,
                                                  const float* __restrict__ tt,
                                                  const int* __restrict__ tlen,
                                                  float* __restrict__ out_i2t,
                                                  float* __restrict__ out_t2i) {
  __shared__ float t_lds[256 * 64];   // transposed [k][t], 64 KB
  __shared__ float v_lds[64 * 260];   // [v][k] padded, 66.6 KB
  __shared__ float red[64 * 16];      // t2i partials [t][vg]
  __shared__ float t2i_max[64];
  __shared__ float wsum[4];

  const int blk = blockIdx.x;
  const int b = blk >> 6;
  const int q = blk & 63;
  const int tid = threadIdx.x;
  const int tv = tid & 15;   // t group: t = tv*4+j
  const int vg = tid >> 4;   // v group within chunk: v = chunk*64 + vg*4 + i

  // stage T transposed: t_lds[k*64 + t]
#pragma unroll
  for (int it = 0; it < 16; ++it) {
    const int id = it * 256 + tid;
    const int t = id >> 6;
    const int kq = id & 63;
    float4 g = *(const float4*)&tt[(q * NL + t) * NE + kq * 4];
    t_lds[(kq * 4 + 0) * 64 + t] = g.x;
    t_lds[(kq * 4 + 1) * 64 + t] = g.y;
    t_lds[(kq * 4 + 2) * 64 + t] = g.z;
    t_lds[(kq * 4 + 3) * 64 + t] = g.w;
  }
  if (tid < 64) t2i_max[tid] = -1e30f;

  float i2t_part = 0.0f;

  for (int chunk = 0; chunk < 4; ++chunk) {
    __syncthreads();  // protect v_lds/red reuse (and T staging on first iter)
    // stage V chunk: 64 rows x 256 k
#pragma unroll
    for (int it = 0; it < 16; ++it) {
      const int id = it * 256 + tid;
      const int r = id >> 6;
      const int kq = id & 63;
      int row = chunk * 64 + r;
      if (row > NV - 1) row = NV - 1;  // clamp padded rows
      *(float4*)&v_lds[r * 260 + kq * 4] =
          *(const float4*)&vt[(b * NV + row) * NE + kq * 4];
    }
    __syncthreads();

    float acc[4][4];
#pragma unroll
    for (int i = 0; i < 4; ++i)
#pragma unroll
      for (int j = 0; j < 4; ++j) acc[i][j] = 0.0f;

    for (int k = 0; k < 256; k += 4) {
      float a[4][4], tb[4][4];
#pragma unroll
      for (int i = 0; i < 4; ++i) {
        float4 v4 = *(const float4*)&v_lds[(vg * 4 + i) * 260 + k];
        a[i][0] = v4.x; a[i][1] = v4.y; a[i][2] = v4.z; a[i][3] = v4.w;
      }
#pragma unroll
      for (int u = 0; u < 4; ++u) {
        float4 v4 = *(const float4*)&t_lds[(k + u) * 64 + tv * 4];
        tb[u][0] = v4.x; tb[u][1] = v4.y; tb[u][2] = v4.z; tb[u][3] = v4.w;
      }
#pragma unroll
      for (int u = 0; u < 4; ++u)
#pragma unroll
        for (int i = 0; i < 4; ++i)
#pragma unroll
          for (int j = 0; j < 4; ++j) acc[i][j] += a[i][u] * tb[u][j];
    }

    const int vbase = chunk * 64 + vg * 4;
    // i2t: per-row max over all 64 t (4 local + 16 lanes sharing this v row)
#pragma unroll
    for (int i = 0; i < 4; ++i) {
      float m = fmaxf(fmaxf(acc[i][0], acc[i][1]), fmaxf(acc[i][2], acc[i][3]));
#pragma unroll
      for (int off = 1; off < 16; off <<= 1) m = fmaxf(m, __shfl_xor(m, off));
      if (tv == 0 && (vbase + i) < NV) i2t_part += m;
    }
    // t2i: per-col max over this thread's valid rows -> LDS scratch
#pragma unroll
    for (int j = 0; j < 4; ++j) {
      float m = -1e30f;
#pragma unroll
      for (int i = 0; i < 4; ++i)
        if ((vbase + i) < NV) m = fmaxf(m, acc[i][j]);
      red[(tv * 4 + j) * 16 + vg] = m;
    }
    __syncthreads();
    if (tid < 64) {
      float m = t2i_max[tid];
#pragma unroll
      for (int g = 0; g < 16; ++g) m = fmaxf(m, red[tid * 16 + g]);
      t2i_max[tid] = m;
    }
  }

  // i2t block reduction
  float s = i2t_part;
#pragma unroll
  for (int off = 1; off < 64; off <<= 1) s += __shfl_xor(s, off);
  if ((tid & 63) == 0) wsum[tid >> 6] = s;
  __syncthreads();
  if (tid == 0)
    out_i2t[b * NB + q] = (wsum[0] + wsum[1] + wsum[2] + wsum[3]) / (float)NV;

  // t2i masked sum (thread t owns t2i_max[t]; it wrote it last, no sync needed)
  if (tid < 64) {
    const int len = tlen[b];
    float v = (tid < len) ? t2i_max[tid] : 0.0f;
#pragma unroll
    for (int off = 1; off < 64; off <<= 1) v += __shfl_xor(v, off);
    if (tid == 0) out_t2i[b * NB + q] = v / fmaxf((float)len, 1e-6f);
  }
}

extern "C" void kernel_launch(void* const* d_in, const int* in_sizes, int n_in,
                              void* d_out, int out_size, void* d_ws, size_t ws_size,
                              hipStream_t stream) {
  (void)in_sizes; (void)n_in; (void)out_size; (void)ws_size;
  const float* visual_cls    = (const float*)d_in[0];
  const float* textual_cls   = (const float*)d_in[1];
  const float* visual_tokens = (const float*)d_in[2];
  const float* textual_tokens= (const float*)d_in[3];
  const int*   text_length   = (const int*)d_in[4];
  const float* Wv  = (const float*)d_in[5];
  const float* bv  = (const float*)d_in[6];
  const float* Wt  = (const float*)d_in[7];
  const float* bt  = (const float*)d_in[8];
  const float* Wvt = (const float*)d_in[9];
  const float* bvt = (const float*)d_in[10];
  const float* Wtt = (const float*)d_in[11];
  const float* btt = (const float*)d_in[12];

  float* out   = (float*)d_out;
  float* v_cls = out;                       // 64*256
  float* t_cls = out + NB * NE;             // 64*256
  float* i2t   = out + 2 * NB * NE;         // 64*64
  float* t2i   = i2t + NB * NB;             // 64*64

  float* v_tok = (float*)d_ws;              // 12608*256 f32 (12.9 MB)
  float* t_tok = v_tok + NB * NV * NE;      // 4096*256 f32 (4 MB)

  cls_kernel<<<NB, 256, 0, stream>>>(visual_cls, Wv, bv, v_cls);
  cls_kernel<<<NB, 256, 0, stream>>>(textual_cls, Wt, bt, t_cls);
  tok_kernel<<<(NB * NV) / 32, 256, 0, stream>>>(visual_tokens, Wvt, bvt, v_tok);
  tok_kernel<<<(NB * NL) / 32, 256, 0, stream>>>(textual_tokens, Wtt, btt, t_tok);
  sim_kernel<<<NB * NB, 256, 0, stream>>>(v_tok, t_tok, text_length, i2t, t2i);
}

// Round 2
// 386.460 us; speedup vs baseline: 2.5967x; 2.5967x over previous
//
#include <hip/hip_runtime.h>
#include <hip/hip_bf16.h>

#define NB 64     // batch
#define NV 197    // visual tokens
#define NL 64     // text tokens
#define ND 768    // input dim
#define NE 256    // embed dim

typedef __attribute__((ext_vector_type(8))) short bh8;     // 8 bf16 = 4 VGPR
typedef __attribute__((ext_vector_type(16))) float f32x16; // MFMA 32x32 accum

// ---------------- Kernel 1: cls projection (B x D) @ (D x E) + bias ----------------
__global__ __launch_bounds__(256) void cls_kernel(const float* __restrict__ x,
                                                  const float* __restrict__ W,
                                                  const float* __restrict__ bias,
                                                  float* __restrict__ out) {
  __shared__ float xs[ND];
  const int b = blockIdx.x;
  const int tid = threadIdx.x;
  const float* xr = x + b * ND;
  for (int i = tid; i < ND; i += 256) xs[i] = xr[i];
  __syncthreads();
  float acc = bias[tid];
#pragma unroll 8
  for (int k = 0; k < ND; ++k) acc += xs[k] * W[k * NE + tid];
  out[b * NE + tid] = acc;
}

// ---------------- Kernel 2: token projection + l2norm -> bf16 ----------------
__global__ __launch_bounds__(256) void tok_kernel(const float* __restrict__ X,
                                                  const float* __restrict__ W,
                                                  const float* __restrict__ bias,
                                                  __hip_bfloat16* __restrict__ out) {
  __shared__ float a_lds[32 * 32];       // 4 KB
  __shared__ float w_lds[32 * 256];      // 32 KB
  const int tid = threadIdx.x;
  const int cx = tid & 63;      // col group: cols cx*4..cx*4+3
  const int ry = tid >> 6;      // row group: rows ry*8..ry*8+7
  const int row0 = blockIdx.x * 32;

  float acc[8][4];
#pragma unroll
  for (int r = 0; r < 8; ++r)
#pragma unroll
    for (int j = 0; j < 4; ++j) acc[r][j] = 0.0f;

  for (int kc = 0; kc < ND; kc += 32) {
    {
      const int r = tid >> 3;
      const int kq = tid & 7;
      *(float4*)&a_lds[r * 32 + kq * 4] =
          *(const float4*)&X[(row0 + r) * ND + kc + kq * 4];
    }
#pragma unroll
    for (int it = 0; it < 8; ++it) {
      const int id = it * 256 + tid;
      const int k = id >> 6;
      const int c4 = id & 63;
      *(float4*)&w_lds[k * 256 + c4 * 4] =
          *(const float4*)&W[(kc + k) * NE + c4 * 4];
    }
    __syncthreads();

#pragma unroll
    for (int kk = 0; kk < 8; ++kk) {
      float a[8][4], w[4][4];
#pragma unroll
      for (int r = 0; r < 8; ++r) {
        float4 v4 = *(const float4*)&a_lds[(ry * 8 + r) * 32 + kk * 4];
        a[r][0] = v4.x; a[r][1] = v4.y; a[r][2] = v4.z; a[r][3] = v4.w;
      }
#pragma unroll
      for (int u = 0; u < 4; ++u) {
        float4 v4 = *(const float4*)&w_lds[(kk * 4 + u) * 256 + cx * 4];
        w[u][0] = v4.x; w[u][1] = v4.y; w[u][2] = v4.z; w[u][3] = v4.w;
      }
#pragma unroll
      for (int u = 0; u < 4; ++u)
#pragma unroll
        for (int r = 0; r < 8; ++r)
#pragma unroll
          for (int j = 0; j < 4; ++j) acc[r][j] += a[r][u] * w[u][j];
    }
    __syncthreads();
  }

  const float4 b4 = *(const float4*)&bias[cx * 4];
#pragma unroll
  for (int r = 0; r < 8; ++r) {
    acc[r][0] += b4.x; acc[r][1] += b4.y; acc[r][2] += b4.z; acc[r][3] += b4.w;
    float ssq = acc[r][0] * acc[r][0] + acc[r][1] * acc[r][1] +
                acc[r][2] * acc[r][2] + acc[r][3] * acc[r][3];
#pragma unroll
    for (int off = 32; off > 0; off >>= 1) ssq += __shfl_xor(ssq, off);
    const float scale = 1.0f / fmaxf(sqrtf(ssq), 1e-12f);
    union { ushort4 u4; __hip_bfloat16 h[4]; } pk;
    pk.h[0] = __float2bfloat16(acc[r][0] * scale);
    pk.h[1] = __float2bfloat16(acc[r][1] * scale);
    pk.h[2] = __float2bfloat16(acc[r][2] * scale);
    pk.h[3] = __float2bfloat16(acc[r][3] * scale);
    *(ushort4*)&out[(row0 + ry * 8 + r) * NE + cx * 4] = pk.u4;
  }
}

// ---------------- Kernel 3: chamfer similarity via bf16 MFMA ----------------
// Grid: 512 blocks = 64 q x 8 b-chunks. Block: 256 thr (4 waves).
// Each wave: T[q] (64x256 bf16) fully in registers as B-fragments (128 VGPR),
// owns M-tiles {w, w+4} (rows 32w.. and 128+32w.., padded/clamped to row 196).
// Streams V fragments straight from global (L2-resident) with 4-deep prefetch.
__global__ __launch_bounds__(256, 2) void sim_kernel(
    const __hip_bfloat16* __restrict__ vt,
    const __hip_bfloat16* __restrict__ tt,
    const int* __restrict__ tlen,
    float* __restrict__ out_i2t,
    float* __restrict__ out_t2i) {
  __shared__ float red[4 * 64];  // per-wave per-col max
  __shared__ float wsum[4];      // per-wave i2t partial

  const int blk = blockIdx.x;
  const int q = blk & 63;
  const int bc = blk >> 6;      // 0..7, 8 b's each
  const int tid = threadIdx.x;
  const int l = tid & 63;
  const int w = tid >> 6;       // wave 0..3
  const int lr = l & 31;
  const int hi = l >> 5;

  // ---- load B fragments: T[q], both 32-col tiles, all 16 K-steps ----
  bh8 breg0[16], breg1[16];
  {
    const __hip_bfloat16* T0 = tt + ((size_t)(q * NL) + lr) * NE + hi * 8;
    const __hip_bfloat16* T1 = T0 + 32 * NE;
#pragma unroll
    for (int s = 0; s < 16; ++s) {
      breg0[s] = *(const bh8*)(T0 + s * 16);
      breg1[s] = *(const bh8*)(T1 + s * 16);
    }
  }

  // per-lane V row indices for this wave's two M-tiles (clamp pad rows to 196)
  const int r0 = 32 * w + lr;                       // < 128, always valid
  const int r1 = min(128 + 32 * w + lr, NV - 1);    // clamped

  for (int ib = 0; ib < 8; ++ib) {
    const int b = bc * 8 + ib;
    const __hip_bfloat16* Vb = vt + (size_t)b * NV * NE + hi * 8;
    const __hip_bfloat16* A0 = Vb + (size_t)r0 * NE;
    const __hip_bfloat16* A1 = Vb + (size_t)r1 * NE;

    f32x16 acc00 = {0}, acc01 = {0}, acc10 = {0}, acc11 = {0};

    bh8 a0[4], a1[4];
#pragma unroll
    for (int s = 0; s < 4; ++s) {
      a0[s] = *(const bh8*)(A0 + s * 16);
      a1[s] = *(const bh8*)(A1 + s * 16);
    }
#pragma unroll
    for (int s = 0; s < 16; ++s) {
      bh8 va0 = a0[s & 3], va1 = a1[s & 3];
      if (s < 12) {
        a0[s & 3] = *(const bh8*)(A0 + (s + 4) * 16);
        a1[s & 3] = *(const bh8*)(A1 + (s + 4) * 16);
      }
      acc00 = __builtin_amdgcn_mfma_f32_32x32x16_bf16(va0, breg0[s], acc00, 0, 0, 0);
      acc01 = __builtin_amdgcn_mfma_f32_32x32x16_bf16(va0, breg1[s], acc01, 0, 0, 0);
      acc10 = __builtin_amdgcn_mfma_f32_32x32x16_bf16(va1, breg0[s], acc10, 0, 0, 0);
      acc11 = __builtin_amdgcn_mfma_f32_32x32x16_bf16(va1, breg1[s], acc11, 0, 0, 0);
    }

    // ---- epilogue: D layout: col = lr + 32*n, row = (r&3)+8*(r>>2)+4*hi + 32*tile
    // i2t: per-row max over 64 cols, sum valid rows
    float i2t_sum = 0.0f;
#pragma unroll
    for (int r = 0; r < 16; ++r) {
      {  // mi = 0 (rows 32w + ..., always < 197)
        float m = fmaxf(acc00[r], acc01[r]);
        m = fmaxf(m, __shfl_xor(m, 1));
        m = fmaxf(m, __shfl_xor(m, 2));
        m = fmaxf(m, __shfl_xor(m, 4));
        m = fmaxf(m, __shfl_xor(m, 8));
        m = fmaxf(m, __shfl_xor(m, 16));
        i2t_sum += m;
      }
      {  // mi = 1 (rows 128 + 32w + ...)
        float m = fmaxf(acc10[r], acc11[r]);
        m = fmaxf(m, __shfl_xor(m, 1));
        m = fmaxf(m, __shfl_xor(m, 2));
        m = fmaxf(m, __shfl_xor(m, 4));
        m = fmaxf(m, __shfl_xor(m, 8));
        m = fmaxf(m, __shfl_xor(m, 16));
        const int row = 128 + 32 * w + (r & 3) + 8 * (r >> 2) + 4 * hi;
        if (row < NV) i2t_sum += m;
      }
    }
    i2t_sum += __shfl_xor(i2t_sum, 32);  // combine hi halves (disjoint rows)
    if (l == 0) wsum[w] = i2t_sum;

    // t2i: per-col max over this wave's rows (clamped pad rows are dups: safe)
    float vm0 = -1e30f, vm1 = -1e30f;
#pragma unroll
    for (int r = 0; r < 16; ++r) {
      vm0 = fmaxf(vm0, fmaxf(acc00[r], acc10[r]));
      vm1 = fmaxf(vm1, fmaxf(acc01[r], acc11[r]));
    }
    vm0 = fmaxf(vm0, __shfl_xor(vm0, 32));  // other hi rows, same col
    vm1 = fmaxf(vm1, __shfl_xor(vm1, 32));
    if (hi == 0) red[w * 64 + lr] = vm0;
    else         red[w * 64 + 32 + lr] = vm1;

    __syncthreads();

    if (tid < 64) {
      const int len = tlen[b];
      float m = fmaxf(fmaxf(red[tid], red[64 + tid]),
                      fmaxf(red[128 + tid], red[192 + tid]));
      float v = (tid < len) ? m : 0.0f;
#pragma unroll
      for (int off = 1; off < 64; off <<= 1) v += __shfl_xor(v, off);
      if (tid == 0) {
        out_t2i[b * NB + q] = v / fmaxf((float)len, 1e-6f);
        out_i2t[b * NB + q] = (wsum[0] + wsum[1] + wsum[2] + wsum[3]) / (float)NV;
      }
    }
    __syncthreads();  // protect red/wsum before next b
  }
}

extern "C" void kernel_launch(void* const* d_in, const int* in_sizes, int n_in,
                              void* d_out, int out_size, void* d_ws, size_t ws_size,
                              hipStream_t stream) {
  (void)in_sizes; (void)n_in; (void)out_size; (void)ws_size;
  const float* visual_cls    = (const float*)d_in[0];
  const float* textual_cls   = (const float*)d_in[1];
  const float* visual_tokens = (const float*)d_in[2];
  const float* textual_tokens= (const float*)d_in[3];
  const int*   text_length   = (const int*)d_in[4];
  const float* Wv  = (const float*)d_in[5];
  const float* bv  = (const float*)d_in[6];
  const float* Wt  = (const float*)d_in[7];
  const float* bt  = (const float*)d_in[8];
  const float* Wvt = (const float*)d_in[9];
  const float* bvt = (const float*)d_in[10];
  const float* Wtt = (const float*)d_in[11];
  const float* btt = (const float*)d_in[12];

  float* out   = (float*)d_out;
  float* v_cls = out;                       // 64*256
  float* t_cls = out + NB * NE;             // 64*256
  float* i2t   = out + 2 * NB * NE;         // 64*64
  float* t2i   = i2t + NB * NB;             // 64*64

  __hip_bfloat16* v_tok = (__hip_bfloat16*)d_ws;          // 12608*256 bf16
  __hip_bfloat16* t_tok = v_tok + NB * NV * NE;           // 4096*256 bf16

  cls_kernel<<<NB, 256, 0, stream>>>(visual_cls, Wv, bv, v_cls);
  cls_kernel<<<NB, 256, 0, stream>>>(textual_cls, Wt, bt, t_cls);
  tok_kernel<<<(NB * NV) / 32, 256, 0, stream>>>(visual_tokens, Wvt, bvt, v_tok);
  tok_kernel<<<(NB * NL) / 32, 256, 0, stream>>>(textual_tokens, Wtt, btt, t_tok);
  sim_kernel<<<NB * NB / 8, 256, 0, stream>>>(v_tok, t_tok, text_length, i2t, t2i);
}

// Round 4
// 234.654 us; speedup vs baseline: 4.2766x; 1.6469x over previous
//
#include <hip/hip_runtime.h>
#include <hip/hip_bf16.h>

#define NB 64     // batch
#define NV 197    // visual tokens
#define NL 64     // text tokens
#define ND 768    // input dim
#define NE 256    // embed dim

typedef __attribute__((ext_vector_type(8))) short bh8;     // 8 bf16 = 4 VGPR
typedef __attribute__((ext_vector_type(16))) float f32x16; // MFMA 32x32 accum

__device__ inline ushort f2bf(float x) {
  __hip_bfloat16 h = __float2bfloat16(x);
  return *reinterpret_cast<ushort*>(&h);
}

__device__ inline bh8 cvt8(float4 a, float4 b) {
  union { bh8 v; ushort u[8]; } r;
  r.u[0] = f2bf(a.x); r.u[1] = f2bf(a.y); r.u[2] = f2bf(a.z); r.u[3] = f2bf(a.w);
  r.u[4] = f2bf(b.x); r.u[5] = f2bf(b.y); r.u[6] = f2bf(b.z); r.u[7] = f2bf(b.w);
  return r.v;
}

// ---------- Kernel 1: unified projection (tok + cls) via MFMA ----------
// Grid 526 blocks x 128 thr (2 waves). Block: 32 rows x 256 cols, K=768.
// Wave w: cols w*128..+127 (4 N-tiles of 32).
// A frags: fp32 X rows + cvt (verified mapping: k = 16*ks + 8*hi + e).
// B frags: gathered DIRECTLY from fp32 W[k][n] (no transpose kernel):
//   element e at W[(16*ks + 8*hi + e)*NE + col] — per-k wave-coalesced 128B.
__global__ __launch_bounds__(128, 2) void proj_kernel(
    const float* __restrict__ Xv, const float* __restrict__ Xt,
    const float* __restrict__ Xcv, const float* __restrict__ Xct,
    const float* __restrict__ Wvt, const float* __restrict__ Wtt,
    const float* __restrict__ Wv, const float* __restrict__ Wt,
    const float* __restrict__ bvt, const float* __restrict__ btt,
    const float* __restrict__ bv, const float* __restrict__ bt,
    ushort* __restrict__ v_tok, ushort* __restrict__ t_tok,
    float* __restrict__ v_cls, float* __restrict__ t_cls) {
  __shared__ float ssq_lds[2][32];

  const int blk = blockIdx.x;
  const float* X; const float* W; const float* bias;
  ushort* outb = nullptr; float* outf = nullptr;
  int row0; bool norm;
  if (blk < 394)      { X = Xv;  W = Wvt; bias = bvt; outb = v_tok; row0 = blk * 32;         norm = true; }
  else if (blk < 522) { X = Xt;  W = Wtt; bias = btt; outb = t_tok; row0 = (blk - 394) * 32; norm = true; }
  else if (blk < 524) { X = Xcv; W = Wv;  bias = bv;  outf = v_cls; row0 = (blk - 522) * 32; norm = false; }
  else                { X = Xct; W = Wt;  bias = bt;  outf = t_cls; row0 = (blk - 524) * 32; norm = false; }

  const int tid = threadIdx.x;
  const int l = tid & 63, w = tid >> 6;
  const int lr = l & 31, hi = l >> 5;

  const float* Arow = X + (size_t)(row0 + lr) * ND + hi * 8;
  const float* Wcol = W + w * 128 + lr;   // + k*NE walks k; +32/64/96 for n-tiles

  f32x16 acc0 = {0}, acc1 = {0}, acc2 = {0}, acc3 = {0};

#pragma unroll 2
  for (int ks = 0; ks < 48; ++ks) {
    const float* Ak = Arow + ks * 16;
    float4 a0 = *(const float4*)Ak;
    float4 a1 = *(const float4*)(Ak + 4);
    bh8 af = cvt8(a0, a1);

    const float* Bk = Wcol + (size_t)(ks * 16 + hi * 8) * NE;
    union { bh8 v; ushort u[8]; } b0, b1, b2, b3;
#pragma unroll
    for (int e = 0; e < 8; ++e) {
      const float* Be = Bk + (size_t)e * NE;
      b0.u[e] = f2bf(Be[0]);
      b1.u[e] = f2bf(Be[32]);
      b2.u[e] = f2bf(Be[64]);
      b3.u[e] = f2bf(Be[96]);
    }
    acc0 = __builtin_amdgcn_mfma_f32_32x32x16_bf16(af, b0.v, acc0, 0, 0, 0);
    acc1 = __builtin_amdgcn_mfma_f32_32x32x16_bf16(af, b1.v, acc1, 0, 0, 0);
    acc2 = __builtin_amdgcn_mfma_f32_32x32x16_bf16(af, b2.v, acc2, 0, 0, 0);
    acc3 = __builtin_amdgcn_mfma_f32_32x32x16_bf16(af, b3.v, acc3, 0, 0, 0);
  }

  // bias (per col; C layout: col = lr + n-tile offset, fixed per lane)
  const float bn0 = bias[w * 128 + lr];
  const float bn1 = bias[w * 128 + 32 + lr];
  const float bn2 = bias[w * 128 + 64 + lr];
  const float bn3 = bias[w * 128 + 96 + lr];
#pragma unroll
  for (int r = 0; r < 16; ++r) {
    acc0[r] += bn0; acc1[r] += bn1; acc2[r] += bn2; acc3[r] += bn3;
  }

  if (norm) {
    // per-row ssq: row R(r,hi) = (r&3)+8*(r>>2)+4*hi; reduce cols across
    // 32-lane half-wave (each half-wave owns its own row set), then cross-wave
    // via tiny LDS.
    float p[16];
#pragma unroll
    for (int r = 0; r < 16; ++r)
      p[r] = acc0[r] * acc0[r] + acc1[r] * acc1[r] +
             acc2[r] * acc2[r] + acc3[r] * acc3[r];
#pragma unroll
    for (int off = 1; off < 32; off <<= 1) {
#pragma unroll
      for (int r = 0; r < 16; ++r) p[r] += __shfl_xor(p[r], off);
    }
    if (lr == 0) {
#pragma unroll
      for (int r = 0; r < 16; ++r)
        ssq_lds[w][(r & 3) + 8 * (r >> 2) + 4 * hi] = p[r];
    }
    __syncthreads();
#pragma unroll
    for (int r = 0; r < 16; ++r) {
      const int R = (r & 3) + 8 * (r >> 2) + 4 * hi;
      const float s = ssq_lds[0][R] + ssq_lds[1][R];
      const float scale = 1.0f / fmaxf(sqrtf(s), 1e-12f);
      ushort* orow = outb + (size_t)(row0 + R) * NE + w * 128 + lr;
      orow[0]  = f2bf(acc0[r] * scale);
      orow[32] = f2bf(acc1[r] * scale);
      orow[64] = f2bf(acc2[r] * scale);
      orow[96] = f2bf(acc3[r] * scale);
    }
  } else {
#pragma unroll
    for (int r = 0; r < 16; ++r) {
      const int R = (r & 3) + 8 * (r >> 2) + 4 * hi;
      float* orow = outf + (size_t)(row0 + R) * NE + w * 128 + lr;
      orow[0]  = acc0[r];
      orow[32] = acc1[r];
      orow[64] = acc2[r];
      orow[96] = acc3[r];
    }
  }
}

// ---------- Kernel 2: chamfer similarity via bf16 MFMA (verified R2) ----------
__global__ __launch_bounds__(256, 2) void sim_kernel(
    const __hip_bfloat16* __restrict__ vt,
    const __hip_bfloat16* __restrict__ tt,
    const int* __restrict__ tlen,
    float* __restrict__ out_i2t,
    float* __restrict__ out_t2i) {
  __shared__ float red[4 * 64];
  __shared__ float wsum[4];

  const int blk = blockIdx.x;
  const int q = blk & 63;
  const int bc = blk >> 6;
  const int tid = threadIdx.x;
  const int l = tid & 63;
  const int w = tid >> 6;
  const int lr = l & 31;
  const int hi = l >> 5;

  bh8 breg0[16], breg1[16];
  {
    const __hip_bfloat16* T0 = tt + ((size_t)(q * NL) + lr) * NE + hi * 8;
    const __hip_bfloat16* T1 = T0 + 32 * NE;
#pragma unroll
    for (int s = 0; s < 16; ++s) {
      breg0[s] = *(const bh8*)(T0 + s * 16);
      breg1[s] = *(const bh8*)(T1 + s * 16);
    }
  }

  const int r0 = 32 * w + lr;
  const int r1 = min(128 + 32 * w + lr, NV - 1);

  for (int ib = 0; ib < 8; ++ib) {
    const int b = bc * 8 + ib;
    const __hip_bfloat16* Vb = vt + (size_t)b * NV * NE + hi * 8;
    const __hip_bfloat16* A0 = Vb + (size_t)r0 * NE;
    const __hip_bfloat16* A1 = Vb + (size_t)r1 * NE;

    f32x16 acc00 = {0}, acc01 = {0}, acc10 = {0}, acc11 = {0};

    bh8 a0[4], a1[4];
#pragma unroll
    for (int s = 0; s < 4; ++s) {
      a0[s] = *(const bh8*)(A0 + s * 16);
      a1[s] = *(const bh8*)(A1 + s * 16);
    }
#pragma unroll
    for (int s = 0; s < 16; ++s) {
      bh8 va0 = a0[s & 3], va1 = a1[s & 3];
      if (s < 12) {
        a0[s & 3] = *(const bh8*)(A0 + (s + 4) * 16);
        a1[s & 3] = *(const bh8*)(A1 + (s + 4) * 16);
      }
      acc00 = __builtin_amdgcn_mfma_f32_32x32x16_bf16(va0, breg0[s], acc00, 0, 0, 0);
      acc01 = __builtin_amdgcn_mfma_f32_32x32x16_bf16(va0, breg1[s], acc01, 0, 0, 0);
      acc10 = __builtin_amdgcn_mfma_f32_32x32x16_bf16(va1, breg0[s], acc10, 0, 0, 0);
      acc11 = __builtin_amdgcn_mfma_f32_32x32x16_bf16(va1, breg1[s], acc11, 0, 0, 0);
    }

    float i2t_sum = 0.0f;
#pragma unroll
    for (int r = 0; r < 16; ++r) {
      {
        float m = fmaxf(acc00[r], acc01[r]);
        m = fmaxf(m, __shfl_xor(m, 1));
        m = fmaxf(m, __shfl_xor(m, 2));
        m = fmaxf(m, __shfl_xor(m, 4));
        m = fmaxf(m, __shfl_xor(m, 8));
        m = fmaxf(m, __shfl_xor(m, 16));
        i2t_sum += m;
      }
      {
        float m = fmaxf(acc10[r], acc11[r]);
        m = fmaxf(m, __shfl_xor(m, 1));
        m = fmaxf(m, __shfl_xor(m, 2));
        m = fmaxf(m, __shfl_xor(m, 4));
        m = fmaxf(m, __shfl_xor(m, 8));
        m = fmaxf(m, __shfl_xor(m, 16));
        const int row = 128 + 32 * w + (r & 3) + 8 * (r >> 2) + 4 * hi;
        if (row < NV) i2t_sum += m;
      }
    }
    i2t_sum += __shfl_xor(i2t_sum, 32);
    if (l == 0) wsum[w] = i2t_sum;

    float vm0 = -1e30f, vm1 = -1e30f;
#pragma unroll
    for (int r = 0; r < 16; ++r) {
      vm0 = fmaxf(vm0, fmaxf(acc00[r], acc10[r]));
      vm1 = fmaxf(vm1, fmaxf(acc01[r], acc11[r]));
    }
    vm0 = fmaxf(vm0, __shfl_xor(vm0, 32));
    vm1 = fmaxf(vm1, __shfl_xor(vm1, 32));
    if (hi == 0) red[w * 64 + lr] = vm0;
    else         red[w * 64 + 32 + lr] = vm1;

    __syncthreads();

    if (tid < 64) {
      const int len = tlen[b];
      float m = fmaxf(fmaxf(red[tid], red[64 + tid]),
                      fmaxf(red[128 + tid], red[192 + tid]));
      float v = (tid < len) ? m : 0.0f;
#pragma unroll
      for (int off = 1; off < 64; off <<= 1) v += __shfl_xor(v, off);
      if (tid == 0) {
        out_t2i[b * NB + q] = v / fmaxf((float)len, 1e-6f);
        out_i2t[b * NB + q] = (wsum[0] + wsum[1] + wsum[2] + wsum[3]) / (float)NV;
      }
    }
    __syncthreads();
  }
}

extern "C" void kernel_launch(void* const* d_in, const int* in_sizes, int n_in,
                              void* d_out, int out_size, void* d_ws, size_t ws_size,
                              hipStream_t stream) {
  (void)in_sizes; (void)n_in; (void)out_size; (void)ws_size;
  const float* visual_cls    = (const float*)d_in[0];
  const float* textual_cls   = (const float*)d_in[1];
  const float* visual_tokens = (const float*)d_in[2];
  const float* textual_tokens= (const float*)d_in[3];
  const int*   text_length   = (const int*)d_in[4];
  const float* Wv  = (const float*)d_in[5];
  const float* bv  = (const float*)d_in[6];
  const float* Wt  = (const float*)d_in[7];
  const float* bt  = (const float*)d_in[8];
  const float* Wvt = (const float*)d_in[9];
  const float* bvt = (const float*)d_in[10];
  const float* Wtt = (const float*)d_in[11];
  const float* btt = (const float*)d_in[12];

  float* out   = (float*)d_out;
  float* v_cls = out;                       // 64*256
  float* t_cls = out + NB * NE;             // 64*256
  float* i2t   = out + 2 * NB * NE;         // 64*64
  float* t2i   = i2t + NB * NB;             // 64*64

  ushort* wsb   = (ushort*)d_ws;
  ushort* v_tok = wsb;                                  // 12608*256 bf16
  ushort* t_tok = v_tok + (size_t)NB * NV * NE;         // 4096*256 bf16

  proj_kernel<<<526, 128, 0, stream>>>(visual_tokens, textual_tokens,
                                       visual_cls, textual_cls,
                                       Wvt, Wtt, Wv, Wt,
                                       bvt, btt, bv, bt,
                                       v_tok, t_tok, v_cls, t_cls);
  sim_kernel<<<NB * NB / 8, 256, 0, stream>>>((const __hip_bfloat16*)v_tok,
                                              (const __hip_bfloat16*)t_tok,
                                              text_length, i2t, t2i);
}